// Round 1
// baseline (859.619 us; speedup 1.0000x reference)
//
#include <hip/hip_runtime.h>
#include <math.h>

#define N 4096
#define IN_F 256
#define OUT_F 512
#define H 8
#define D 64
#define NEG 0.2f

#define IT 32        // i-tile rows per block (attention)
#define JCHUNK 1024  // j range per block (grid.y = N/JCHUNK = 4)

__device__ __forceinline__ float leaky(float x) { return fmaxf(x, NEG * x); }

// ---------------- K1: h = inp @ W^T  (4096x256 @ 256x512) ----------------
// BM=64, BN=64, BK=16, 256 threads, 4x4 per thread.
__global__ __launch_bounds__(256) void k_gemm(const float* __restrict__ inp,
                                              const float* __restrict__ W,
                                              float* __restrict__ hbuf) {
    __shared__ float As[16][64];  // [k][i]
    __shared__ float Bs[16][64];  // [k][o]
    const int t = threadIdx.x;
    const int bi = blockIdx.x;   // M tile
    const int bo = blockIdx.y;   // N tile
    const int ty = t >> 4, tx = t & 15;
    const int lr = t >> 2;            // 0..63
    const int lk = (t & 3) << 2;      // 0,4,8,12
    float acc[4][4] = {};
    for (int k0 = 0; k0 < IN_F; k0 += 16) {
        float4 av = *(const float4*)&inp[(size_t)(bi * 64 + lr) * IN_F + k0 + lk];
        float4 bv = *(const float4*)&W[(size_t)(bo * 64 + lr) * IN_F + k0 + lk];
        __syncthreads();
        As[lk + 0][lr] = av.x; As[lk + 1][lr] = av.y; As[lk + 2][lr] = av.z; As[lk + 3][lr] = av.w;
        Bs[lk + 0][lr] = bv.x; Bs[lk + 1][lr] = bv.y; Bs[lk + 2][lr] = bv.z; Bs[lk + 3][lr] = bv.w;
        __syncthreads();
#pragma unroll
        for (int k = 0; k < 16; ++k) {
            float4 a4 = *(const float4*)&As[k][ty * 4];
            float4 b4 = *(const float4*)&Bs[k][tx * 4];
            float a[4] = {a4.x, a4.y, a4.z, a4.w};
            float b[4] = {b4.x, b4.y, b4.z, b4.w};
#pragma unroll
            for (int r = 0; r < 4; ++r)
#pragma unroll
                for (int c = 0; c < 4; ++c) acc[r][c] = fmaf(a[r], b[c], acc[r][c]);
        }
    }
#pragma unroll
    for (int r = 0; r < 4; ++r) {
        float4 v = {acc[r][0], acc[r][1], acc[r][2], acc[r][3]};
        *(float4*)&hbuf[(size_t)(bi * 64 + ty * 4 + r) * OUT_F + bo * 64 + tx * 4] = v;
    }
}

// ---------------- K2: scores s[h][i] = sum_d h[i][h*64+d]*a_left[h][d] ----
__global__ __launch_bounds__(256) void k_scores(const float* __restrict__ hbuf,
                                                const float* __restrict__ a_left,
                                                float* __restrict__ s) {
    int t = blockIdx.x * 256 + threadIdx.x;  // 0..N*H-1
    int i = t >> 3, hh = t & 7;
    const float* hp = &hbuf[(size_t)i * OUT_F + hh * D];
    const float* ap = &a_left[hh * D];
    float sum = 0.f;
#pragma unroll
    for (int d = 0; d < D; d += 4) {
        float4 hv = *(const float4*)&hp[d];
        float4 av = *(const float4*)&ap[d];
        sum += hv.x * av.x + hv.y * av.y + hv.z * av.z + hv.w * av.w;
    }
    s[hh * N + i] = sum;
}

// ---------------- K2b: per-head max of s ----------------------------------
__global__ __launch_bounds__(256) void k_smax(const float* __restrict__ s,
                                              float* __restrict__ smax) {
    int hh = blockIdx.x;
    float m = -1e30f;
    for (int i = threadIdx.x; i < N; i += 256) m = fmaxf(m, s[hh * N + i]);
    for (int off = 32; off; off >>= 1) m = fmaxf(m, __shfl_down(m, off, 64));
    __shared__ float red[4];
    if ((threadIdx.x & 63) == 0) red[threadIdx.x >> 6] = m;
    __syncthreads();
    if (threadIdx.x == 0) smax[hh] = fmaxf(fmaxf(red[0], red[1]), fmaxf(red[2], red[3]));
}

// ---------------- K3: per-row max of A ------------------------------------
__global__ __launch_bounds__(256) void k_rowmax(const float* __restrict__ A,
                                                float* __restrict__ rmax) {
    int i = blockIdx.x;
    const float* row = &A[(size_t)i * N];
    float m = -1e30f;
    for (int j = threadIdx.x * 4; j < N; j += 256 * 4) {
        float4 v = *(const float4*)&row[j];
        m = fmaxf(fmaxf(fmaxf(m, v.x), fmaxf(v.y, v.z)), v.w);
    }
    for (int off = 32; off; off >>= 1) m = fmaxf(m, __shfl_down(m, off, 64));
    __shared__ float red[4];
    if ((threadIdx.x & 63) == 0) red[threadIdx.x >> 6] = m;
    __syncthreads();
    if (threadIdx.x == 0) rmax[i] = fmaxf(fmaxf(red[0], red[1]), fmaxf(red[2], red[3]));
}

// ---------------- K4: fused attention (all heads per block) ---------------
// Block: 256 threads, i-tile = 32 rows, j-chunk = 1024 (grid = 128 x 4).
// S role:  thread t -> (sh = t>>5, si = t&31), 16 weights per 16-j subtile.
// PV role: thread t -> (ph = t>>5, ig = (t>>2)&7, dg = t&3); acc 4i x 16d.
__global__ __launch_bounds__(256, 2) void k_attn(const float* __restrict__ A,
                                                 const float* __restrict__ hbuf,
                                                 const float* __restrict__ s,
                                                 const float* __restrict__ smax,
                                                 const float* __restrict__ rmax,
                                                 float* __restrict__ outAcc,
                                                 float* __restrict__ Z) {
    __shared__ float Ast[IT][68];       // A stage: 32 x 64 cols (pad 68: fp4-aligned)
    __shared__ float Wl[H][IT][17];     // weights for current 16-j subtile (pad 17)
    __shared__ float Ht[16][OUT_F];     // h stage: 16 j-rows x 512
    __shared__ float Sl[H][IT];
    __shared__ float Mb[H][IT];

    const int t = threadIdx.x;
    const int i0 = blockIdx.x * IT;
    const int j0 = blockIdx.y * JCHUNK;
    const int sh = t >> 5, si = t & 31;
    const int ph = t >> 5, ig = (t >> 2) & 7, dg = t & 3;

    {
        float sv = s[sh * N + i0 + si];
        Sl[sh][si] = sv;
        Mb[sh][si] = leaky(sv + smax[sh]) + rmax[i0 + si];
    }
    __syncthreads();

    const float s_i = Sl[sh][si];
    const float mb = Mb[sh][si];
    float zsum = 0.f;
    float acc[4][16] = {};
    const int colbase = ph * 64 + dg * 16;

    for (int jb = j0; jb < j0 + JCHUNK; jb += 64) {
        // stage A tile 32 x 64 (coalesced 256B rows)
#pragma unroll
        for (int q = 0; q < 2; ++q) {
            int idx = t + q * 256;           // 0..511 float4s
            int r = idx >> 4;                // 0..31
            int c4 = idx & 15;               // 0..15
            float4 v = *(const float4*)&A[(size_t)(i0 + r) * N + jb + c4 * 4];
            *(float4*)&Ast[r][c4 * 4] = v;
        }
#pragma unroll
        for (int sub = 0; sub < 4; ++sub) {
            __syncthreads();  // prev PV done (Ht/Wl reuse) + Ast ready
            // stage Ht: 16 x 512 floats, fully coalesced
#pragma unroll
            for (int q = 0; q < 8; ++q) {
                int fi = q * 256 + t;
                int r = fi >> 7;
                int c4 = fi & 127;
                *(float4*)&Ht[r][c4 * 4] =
                    *(const float4*)&hbuf[(size_t)(jb + sub * 16 + r) * OUT_F + c4 * 4];
            }
            // S-phase: weights for this 16-j subtile
#pragma unroll
            for (int jj4 = 0; jj4 < 4; ++jj4) {
                int jloc = sub * 16 + jj4 * 4;
                float4 av = *(const float4*)&Ast[si][jloc];
                float4 sj = *(const float4*)&s[sh * N + jb + jloc];
                float w0 = __expf(leaky(s_i + sj.x) + av.x - mb);
                float w1 = __expf(leaky(s_i + sj.y) + av.y - mb);
                float w2 = __expf(leaky(s_i + sj.z) + av.z - mb);
                float w3 = __expf(leaky(s_i + sj.w) + av.w - mb);
                zsum += (w0 + w1) + (w2 + w3);
                Wl[sh][si][jj4 * 4 + 0] = w0;
                Wl[sh][si][jj4 * 4 + 1] = w1;
                Wl[sh][si][jj4 * 4 + 2] = w2;
                Wl[sh][si][jj4 * 4 + 3] = w3;
            }
            __syncthreads();  // Ht + Wl visible
            // PV: acc[4][16] += w * h
            for (int jj = 0; jj < 16; ++jj) {
                float w0 = Wl[ph][ig * 4 + 0][jj];
                float w1 = Wl[ph][ig * 4 + 1][jj];
                float w2 = Wl[ph][ig * 4 + 2][jj];
                float w3 = Wl[ph][ig * 4 + 3][jj];
                float4 h0 = *(const float4*)&Ht[jj][colbase + 0];
                float4 h1 = *(const float4*)&Ht[jj][colbase + 4];
                float4 h2 = *(const float4*)&Ht[jj][colbase + 8];
                float4 h3 = *(const float4*)&Ht[jj][colbase + 12];
                float hv[16] = {h0.x, h0.y, h0.z, h0.w, h1.x, h1.y, h1.z, h1.w,
                                h2.x, h2.y, h2.z, h2.w, h3.x, h3.y, h3.z, h3.w};
                float wv[4] = {w0, w1, w2, w3};
#pragma unroll
                for (int r = 0; r < 4; ++r)
#pragma unroll
                    for (int c = 0; c < 16; ++c) acc[r][c] = fmaf(wv[r], hv[c], acc[r][c]);
            }
        }
    }

    // flush partial sums
#pragma unroll
    for (int r = 0; r < 4; ++r) {
        float* op = &outAcc[(size_t)(i0 + ig * 4 + r) * OUT_F + colbase];
#pragma unroll
        for (int c = 0; c < 16; ++c) atomicAdd(&op[c], acc[r][c]);
    }
    atomicAdd(&Z[sh * N + i0 + si], zsum);
}

// ---------------- K5: normalize -------------------------------------------
__global__ __launch_bounds__(256) void k_norm(float* __restrict__ out,
                                              const float* __restrict__ Z) {
    int idx = blockIdx.x * 256 + threadIdx.x;
    int i = idx >> 9, hd = idx & 511, hh = hd >> 6;
    out[idx] = out[idx] / Z[hh * N + i];
}

extern "C" void kernel_launch(void* const* d_in, const int* in_sizes, int n_in,
                              void* d_out, int out_size, void* d_ws, size_t ws_size,
                              hipStream_t stream) {
    const float* inp = (const float*)d_in[0];
    const float* A = (const float*)d_in[1];
    const float* W = (const float*)d_in[2];
    const float* a_left = (const float*)d_in[3];
    float* out = (float*)d_out;

    float* hbuf = (float*)d_ws;                  // 4096*512
    float* s = hbuf + (size_t)N * OUT_F;         // 8*4096
    float* smax = s + (size_t)H * N;             // 8
    float* rmax = smax + 8;                      // 4096
    float* Z = rmax + N;                         // 8*4096

    hipMemsetAsync(out, 0, (size_t)N * OUT_F * sizeof(float), stream);
    hipMemsetAsync(Z, 0, (size_t)H * N * sizeof(float), stream);

    k_gemm<<<dim3(N / 64, OUT_F / 64), 256, 0, stream>>>(inp, W, hbuf);
    k_scores<<<dim3(N * H / 256), 256, 0, stream>>>(hbuf, a_left, s);
    k_smax<<<dim3(H), 256, 0, stream>>>(s, smax);
    k_rowmax<<<dim3(N), 256, 0, stream>>>(A, rmax);
    k_attn<<<dim3(N / IT, N / JCHUNK), 256, 0, stream>>>(A, hbuf, s, smax, rmax, out, Z);
    k_norm<<<dim3(N * OUT_F / 256), 256, 0, stream>>>(out, Z);
}

// Round 2
// 307.093 us; speedup vs baseline: 2.7992x; 2.7992x over previous
//
#include <hip/hip_runtime.h>
#include <math.h>

#define N 4096
#define IN_F 256
#define OUT_F 512
#define H 8
#define D 64
#define NEG 0.2f

typedef __attribute__((ext_vector_type(8))) short bf16x8;
typedef __attribute__((ext_vector_type(4))) float f32x4;

__device__ __forceinline__ float leaky(float x) { return fmaxf(x, NEG * x); }

__device__ __forceinline__ unsigned short f2bf(float x) {
    union { float f; unsigned u; } v; v.f = x;
    unsigned r = v.u + 0x7fff + ((v.u >> 16) & 1);  // RNE
    return (unsigned short)(r >> 16);
}
__device__ __forceinline__ float bf2f(unsigned short b) {
    union { float f; unsigned u; } v; v.u = ((unsigned)b) << 16; return v.f;
}

// ---- K1: h = inp @ W^T per (i-tile, head); epilogue emits hbT (bf16, [h][d][j]) + scores s
__global__ __launch_bounds__(256) void k_gemm(const float* __restrict__ inp,
                                              const float* __restrict__ W,
                                              const float* __restrict__ a_left,
                                              unsigned short* __restrict__ hbT,
                                              float* __restrict__ s) {
    __shared__ float As[16][64];
    __shared__ float Bs[16][64];
    __shared__ unsigned short h_st[64][72];  // [i_local][d_local] bf16, pad 72
    const int t = threadIdx.x;
    const int bi = blockIdx.x;
    const int head = blockIdx.y;
    const int ty = t >> 4, tx = t & 15;
    const int lr = t >> 2;
    const int lk = (t & 3) << 2;
    float acc[4][4] = {};
    for (int k0 = 0; k0 < IN_F; k0 += 16) {
        float4 av = *(const float4*)&inp[(size_t)(bi * 64 + lr) * IN_F + k0 + lk];
        float4 bv = *(const float4*)&W[(size_t)(head * 64 + lr) * IN_F + k0 + lk];
        __syncthreads();
        As[lk + 0][lr] = av.x; As[lk + 1][lr] = av.y; As[lk + 2][lr] = av.z; As[lk + 3][lr] = av.w;
        Bs[lk + 0][lr] = bv.x; Bs[lk + 1][lr] = bv.y; Bs[lk + 2][lr] = bv.z; Bs[lk + 3][lr] = bv.w;
        __syncthreads();
#pragma unroll
        for (int k = 0; k < 16; ++k) {
            float4 a4 = *(const float4*)&As[k][ty * 4];
            float4 b4 = *(const float4*)&Bs[k][tx * 4];
            float a[4] = {a4.x, a4.y, a4.z, a4.w};
            float b[4] = {b4.x, b4.y, b4.z, b4.w};
#pragma unroll
            for (int r = 0; r < 4; ++r)
#pragma unroll
                for (int c = 0; c < 4; ++c) acc[r][c] = fmaf(a[r], b[c], acc[r][c]);
        }
    }
    // scores: s[head][i] = sum_d h[i][d]*a_left[head][d]; reduce across tx (16-lane groups)
    float aL[4];
#pragma unroll
    for (int c = 0; c < 4; ++c) aL[c] = a_left[head * D + tx * 4 + c];
#pragma unroll
    for (int r = 0; r < 4; ++r) {
        float sp = acc[r][0] * aL[0] + acc[r][1] * aL[1] + acc[r][2] * aL[2] + acc[r][3] * aL[3];
        sp += __shfl_xor(sp, 1); sp += __shfl_xor(sp, 2);
        sp += __shfl_xor(sp, 4); sp += __shfl_xor(sp, 8);
        if (tx == 0) s[head * N + bi * 64 + ty * 4 + r] = sp;
    }
    // stage h tile to LDS as bf16 for transpose
    __syncthreads();
#pragma unroll
    for (int r = 0; r < 4; ++r) {
        ushort4 v;
        v.x = f2bf(acc[r][0]); v.y = f2bf(acc[r][1]);
        v.z = f2bf(acc[r][2]); v.w = f2bf(acc[r][3]);
        *(ushort4*)&h_st[ty * 4 + r][tx * 4] = v;
    }
    __syncthreads();
    // write hbT[head][d][i] coalesced-ish: thread -> (d = t>>2, iq = (t&3)*16)
    {
        const int d = t >> 2, iq = (t & 3) * 16;
        unsigned short us[16];
#pragma unroll
        for (int k = 0; k < 16; ++k) us[k] = h_st[iq + k][d];
        unsigned short* dst = &hbT[((size_t)(head * D + d)) * N + bi * 64 + iq];
#pragma unroll
        for (int q = 0; q < 4; ++q) {
            ushort4 v = {us[q * 4 + 0], us[q * 4 + 1], us[q * 4 + 2], us[q * 4 + 3]};
            *(ushort4*)&dst[q * 4] = v;
        }
    }
}

// ---- K2: per-head max of s
__global__ __launch_bounds__(256) void k_smax(const float* __restrict__ s,
                                              float* __restrict__ smax) {
    int hh = blockIdx.x;
    float m = -1e30f;
    for (int i = threadIdx.x; i < N; i += 256) m = fmaxf(m, s[hh * N + i]);
    for (int off = 32; off; off >>= 1) m = fmaxf(m, __shfl_down(m, off, 64));
    __shared__ float red[4];
    if ((threadIdx.x & 63) == 0) red[threadIdx.x >> 6] = m;
    __syncthreads();
    if (threadIdx.x == 0) smax[hh] = fmaxf(fmaxf(red[0], red[1]), fmaxf(red[2], red[3]));
}

// ---- K3: per-row max of A
__global__ __launch_bounds__(256) void k_rowmax(const float* __restrict__ A,
                                                float* __restrict__ rmax) {
    int i = blockIdx.x;
    const float* row = &A[(size_t)i * N];
    float m = -1e30f;
    for (int j = threadIdx.x * 4; j < N; j += 256 * 4) {
        float4 v = *(const float4*)&row[j];
        m = fmaxf(fmaxf(fmaxf(m, v.x), fmaxf(v.y, v.z)), v.w);
    }
    for (int off = 32; off; off >>= 1) m = fmaxf(m, __shfl_down(m, off, 64));
    __shared__ float red[4];
    if ((threadIdx.x & 63) == 0) red[threadIdx.x >> 6] = m;
    __syncthreads();
    if (threadIdx.x == 0) rmax[i] = fmaxf(fmaxf(red[0], red[1]), fmaxf(red[2], red[3]));
}

// ---- K4: fused attention, MFMA PV. Block = (i-tile 64, head). 4 waves; wave w
// owns i-strip w*16..w*16+15, all 64 d. P built in registers in A-frag layout.
__global__ __launch_bounds__(256, 2) void k_attn(const float* __restrict__ A,
                                                 const unsigned short* __restrict__ hbT,
                                                 const float* __restrict__ s,
                                                 const float* __restrict__ smax,
                                                 const float* __restrict__ rmax,
                                                 float* __restrict__ out) {
    __shared__ float A_st[64][68];            // 17.4 KB
    __shared__ unsigned short hT_st[64][72];  // [d][j] bf16, 9.2 KB
    __shared__ float s_row[N];                // 16 KB
    __shared__ float sLi[64], mbL[64];

    const int t = threadIdx.x;
    const int head = blockIdx.y;
    const int i0 = blockIdx.x * 64;
    const int wave = t >> 6, lane = t & 63, quad = lane >> 4, li = lane & 15;
    const int iw = wave * 16;

#pragma unroll
    for (int q = 0; q < 4; ++q) {
        int idx = q * 256 + t;  // float4 index 0..1023
        *(float4*)&s_row[idx * 4] = *(const float4*)&s[head * N + idx * 4];
    }
    if (t < 64) {
        float sv = s[head * N + i0 + t];
        sLi[t] = sv;
        mbL[t] = leaky(sv + smax[head]) + rmax[i0 + t];
    }
    __syncthreads();

    const float s_i = sLi[iw + li];
    const float mb = mbL[iw + li];

    f32x4 acc[4] = {{0, 0, 0, 0}, {0, 0, 0, 0}, {0, 0, 0, 0}, {0, 0, 0, 0}};
    float zsum = 0.f;

    float4 pa[4];  // A-tile prefetch regs (16 floats)
    float4 ph[2];  // h-tile prefetch regs (16 bf16)
    const size_t hbase = (size_t)head * D * N;

    auto load_tile = [&](int jt) {
#pragma unroll
        for (int q = 0; q < 4; ++q) {
            int idx = q * 256 + t;  // 0..1023 float4s of 64x64 A tile
            int r = idx >> 4, c4 = idx & 15;
            pa[q] = *(const float4*)&A[(size_t)(i0 + r) * N + jt + c4 * 4];
        }
#pragma unroll
        for (int q = 0; q < 2; ++q) {
            int idx = q * 256 + t;  // 0..511 units of 8 bf16 (64 d-rows x 8)
            int d = idx >> 3, p8 = idx & 7;
            ph[q] = *(const float4*)&hbT[hbase + (size_t)d * N + jt + p8 * 8];
        }
    };
    load_tile(0);

    for (int jt = 0; jt < N; jt += 64) {
        __syncthreads();  // previous compute done with LDS
#pragma unroll
        for (int q = 0; q < 4; ++q) {
            int idx = q * 256 + t;
            int r = idx >> 4, c4 = idx & 15;
            *(float4*)&A_st[r][c4 * 4] = pa[q];
        }
#pragma unroll
        for (int q = 0; q < 2; ++q) {
            int idx = q * 256 + t;
            int d = idx >> 3, p8 = idx & 7;
            *(float4*)&hT_st[d][p8 * 8] = ph[q];
        }
        __syncthreads();
        if (jt + 64 < N) load_tile(jt + 64);  // prefetch next tile into regs

#pragma unroll
        for (int kh = 0; kh < 2; ++kh) {
            const int jl = kh * 32 + quad * 8;
            float4 a0 = *(const float4*)&A_st[iw + li][jl];
            float4 a1 = *(const float4*)&A_st[iw + li][jl + 4];
            float4 s0 = *(const float4*)&s_row[jt + jl];
            float4 s1 = *(const float4*)&s_row[jt + jl + 4];
            float av[8] = {a0.x, a0.y, a0.z, a0.w, a1.x, a1.y, a1.z, a1.w};
            float sv[8] = {s0.x, s0.y, s0.z, s0.w, s1.x, s1.y, s1.z, s1.w};
            bf16x8 pf;
#pragma unroll
            for (int jj = 0; jj < 8; ++jj) {
                float p = __expf(leaky(s_i + sv[jj]) + av[jj] - mb);
                unsigned short b = f2bf(p);
                zsum += bf2f(b);  // Z from rounded weights (consistency)
                pf[jj] = (short)b;
            }
#pragma unroll
            for (int db = 0; db < 4; ++db) {
                bf16x8 hf = *(const bf16x8*)&hT_st[db * 16 + li][jl];
                acc[db] = __builtin_amdgcn_mfma_f32_16x16x32_bf16(pf, hf, acc[db], 0, 0, 0);
            }
        }
    }

    // row-sum Z: lanes li, li+16, li+32, li+48 hold partial sums for row iw+li
    zsum += __shfl_xor(zsum, 16);
    zsum += __shfl_xor(zsum, 32);

#pragma unroll
    for (int r = 0; r < 4; ++r) {
        float zr = __shfl(zsum, quad * 4 + r, 16);  // z of row iw+quad*4+r
        float inv = 1.f / zr;
        const size_t row = (size_t)(i0 + iw + quad * 4 + r) * OUT_F + head * D;
#pragma unroll
        for (int db = 0; db < 4; ++db) out[row + db * 16 + li] = acc[db][r] * inv;
    }
}

extern "C" void kernel_launch(void* const* d_in, const int* in_sizes, int n_in,
                              void* d_out, int out_size, void* d_ws, size_t ws_size,
                              hipStream_t stream) {
    const float* inp = (const float*)d_in[0];
    const float* A = (const float*)d_in[1];
    const float* W = (const float*)d_in[2];
    const float* a_left = (const float*)d_in[3];
    float* out = (float*)d_out;

    unsigned short* hbT = (unsigned short*)d_ws;             // 8*64*4096 bf16 = 4 MB
    float* s = (float*)((char*)d_ws + (size_t)H * D * N * 2);  // 8*4096 f32
    float* smax = s + (size_t)H * N;                         // 8
    float* rmax = smax + 8;                                  // 4096

    k_gemm<<<dim3(N / 64, H), 256, 0, stream>>>(inp, W, a_left, hbT, s);
    k_smax<<<dim3(H), 256, 0, stream>>>(s, smax);
    k_rowmax<<<dim3(N), 256, 0, stream>>>(A, rmax);
    k_attn<<<dim3(N / 64, H), 256, 0, stream>>>(A, hbT, s, smax, rmax, out);
}

// Round 3
// 285.910 us; speedup vs baseline: 3.0066x; 1.0741x over previous
//
#include <hip/hip_runtime.h>
#include <math.h>

#define N 4096
#define IN_F 256
#define OUT_F 512
#define H 8
#define D 64
#define NEG 0.2f
#define JC 2048  // j-chunk per block (grid.z = 2)

typedef __attribute__((ext_vector_type(8))) short bf16x8;
typedef __attribute__((ext_vector_type(4))) float f32x4;

__device__ __forceinline__ float leaky(float x) { return fmaxf(x, NEG * x); }

__device__ __forceinline__ unsigned short f2bf(float x) {
    union { float f; unsigned u; } v; v.f = x;
    unsigned r = v.u + 0x7fff + ((v.u >> 16) & 1);  // RNE
    return (unsigned short)(r >> 16);
}

// monotone float<->uint map for atomicMax-based float max
__device__ __forceinline__ unsigned fmap(float x) {
    union { float f; unsigned u; } v; v.f = x;
    return (v.u & 0x80000000u) ? ~v.u : (v.u | 0x80000000u);
}
__device__ __forceinline__ float funmap(unsigned m) {
    union { float f; unsigned u; } v;
    v.u = (m & 0x80000000u) ? (m & 0x7fffffffu) : ~m;
    return v.f;
}

// async 16B global->LDS DMA
__device__ __forceinline__ void dma16(const void* g, void* l) {
    __builtin_amdgcn_global_load_lds((const __attribute__((address_space(1))) void*)g,
                                     (__attribute__((address_space(3))) void*)l, 16, 0, 0);
}

// ---- K1: h = inp @ W^T per (i-tile, head); emits hbT (bf16, [h][d][j]) + s + atomicMax smaxU
__global__ __launch_bounds__(256) void k_gemm(const float* __restrict__ inp,
                                              const float* __restrict__ W,
                                              const float* __restrict__ a_left,
                                              unsigned short* __restrict__ hbT,
                                              float* __restrict__ s,
                                              unsigned* __restrict__ smaxU) {
    __shared__ float As[16][64];
    __shared__ float Bs[16][64];
    __shared__ unsigned short h_st[64][72];
    const int t = threadIdx.x;
    const int bi = blockIdx.x;
    const int head = blockIdx.y;
    const int ty = t >> 4, tx = t & 15;
    const int lr = t >> 2;
    const int lk = (t & 3) << 2;
    float acc[4][4] = {};
    for (int k0 = 0; k0 < IN_F; k0 += 16) {
        float4 av = *(const float4*)&inp[(size_t)(bi * 64 + lr) * IN_F + k0 + lk];
        float4 bv = *(const float4*)&W[(size_t)(head * 64 + lr) * IN_F + k0 + lk];
        __syncthreads();
        As[lk + 0][lr] = av.x; As[lk + 1][lr] = av.y; As[lk + 2][lr] = av.z; As[lk + 3][lr] = av.w;
        Bs[lk + 0][lr] = bv.x; Bs[lk + 1][lr] = bv.y; Bs[lk + 2][lr] = bv.z; Bs[lk + 3][lr] = bv.w;
        __syncthreads();
#pragma unroll
        for (int k = 0; k < 16; ++k) {
            float4 a4 = *(const float4*)&As[k][ty * 4];
            float4 b4 = *(const float4*)&Bs[k][tx * 4];
            float a[4] = {a4.x, a4.y, a4.z, a4.w};
            float b[4] = {b4.x, b4.y, b4.z, b4.w};
#pragma unroll
            for (int r = 0; r < 4; ++r)
#pragma unroll
                for (int c = 0; c < 4; ++c) acc[r][c] = fmaf(a[r], b[c], acc[r][c]);
        }
    }
    float aL[4];
#pragma unroll
    for (int c = 0; c < 4; ++c) aL[c] = a_left[head * D + tx * 4 + c];
#pragma unroll
    for (int r = 0; r < 4; ++r) {
        float sp = acc[r][0] * aL[0] + acc[r][1] * aL[1] + acc[r][2] * aL[2] + acc[r][3] * aL[3];
        sp += __shfl_xor(sp, 1); sp += __shfl_xor(sp, 2);
        sp += __shfl_xor(sp, 4); sp += __shfl_xor(sp, 8);
        if (tx == 0) {
            s[head * N + bi * 64 + ty * 4 + r] = sp;
            atomicMax(&smaxU[head], fmap(sp));
        }
    }
    __syncthreads();
#pragma unroll
    for (int r = 0; r < 4; ++r) {
        ushort4 v;
        v.x = f2bf(acc[r][0]); v.y = f2bf(acc[r][1]);
        v.z = f2bf(acc[r][2]); v.w = f2bf(acc[r][3]);
        *(ushort4*)&h_st[ty * 4 + r][tx * 4] = v;
    }
    __syncthreads();
    {
        const int d = t >> 2, iq = (t & 3) * 16;
        unsigned short us[16];
#pragma unroll
        for (int k = 0; k < 16; ++k) us[k] = h_st[iq + k][d];
        unsigned short* dst = &hbT[((size_t)(head * D + d)) * N + bi * 64 + iq];
#pragma unroll
        for (int q = 0; q < 4; ++q) {
            ushort4 v = {us[q * 4 + 0], us[q * 4 + 1], us[q * 4 + 2], us[q * 4 + 3]};
            *(ushort4*)&dst[q * 4] = v;
        }
    }
}

// ---- K2: per-row max of A
__global__ __launch_bounds__(256) void k_rowmax(const float* __restrict__ A,
                                                float* __restrict__ rmax) {
    int i = blockIdx.x;
    const float* row = &A[(size_t)i * N];
    float m = -1e30f;
    for (int j = threadIdx.x * 4; j < N; j += 256 * 4) {
        float4 v = *(const float4*)&row[j];
        m = fmaxf(fmaxf(fmaxf(m, v.x), fmaxf(v.y, v.z)), v.w);
    }
    for (int off = 32; off; off >>= 1) m = fmaxf(m, __shfl_down(m, off, 64));
    __shared__ float red[4];
    if ((threadIdx.x & 63) == 0) red[threadIdx.x >> 6] = m;
    __syncthreads();
    if (threadIdx.x == 0) rmax[i] = fmaxf(fmaxf(red[0], red[1]), fmaxf(red[2], red[3]));
}

// ---- K3: fused attention. Block = (64 i-rows, head, j-half). DMA staging + XOR-swizzled LDS.
__global__ __launch_bounds__(256, 4) void k_attn(const float* __restrict__ A,
                                                 const unsigned short* __restrict__ hbT,
                                                 const float* __restrict__ s,
                                                 const unsigned* __restrict__ smaxU,
                                                 const float* __restrict__ rmax,
                                                 float* __restrict__ out,
                                                 float* __restrict__ Z) {
    __shared__ float A_st[64 * 16 * 4];          // 1024 slots x 16B, swizzled
    __shared__ unsigned short hT_st[64 * 8 * 8]; // 512 slots x 16B, swizzled
    __shared__ float s_ch[JC];

    const int t = threadIdx.x;
    const int i0 = blockIdx.x * 64;
    const int head = blockIdx.y;
    const int j0 = blockIdx.z * JC;
    const int lane = t & 63, wave = t >> 6, quad = lane >> 4, li = lane & 15;
    const int iw = wave * 16;
    const int myrow = i0 + iw + li;

    // preload s chunk (read-only over whole loop)
#pragma unroll
    for (int q = 0; q < 2; ++q) {
        int idx = q * 256 + t;
        *(float4*)&s_ch[idx * 4] = *(const float4*)&s[head * N + j0 + idx * 4];
    }
    const float s_i = s[head * N + myrow];
    const float mb = leaky(s_i + funmap(smaxU[head])) + rmax[myrow];

    // DMA source pointers (global side carries the swizzle) + LDS slots
    const float* gA[4]; void* lA[4];
#pragma unroll
    for (int q = 0; q < 4; ++q) {
        int slot = q * 256 + t;
        int r = slot >> 4, c4p = slot & 15;
        int c4 = c4p ^ (r & 7);
        gA[q] = &A[(size_t)(i0 + r) * N + j0 + c4 * 4];
        lA[q] = (void*)&A_st[slot * 4];
    }
    const unsigned short* gH[2]; void* lH[2];
#pragma unroll
    for (int q = 0; q < 2; ++q) {
        int slot = q * 256 + t;
        int r = slot >> 3, u = slot & 7;
        int uc = u ^ (r & 7);
        gH[q] = &hbT[(size_t)head * D * N + (size_t)r * N + j0 + uc * 8];
        lH[q] = (void*)&hT_st[slot * 8];
    }

    f32x4 acc[4] = {{0, 0, 0, 0}, {0, 0, 0, 0}, {0, 0, 0, 0}, {0, 0, 0, 0}};
    float zsum = 0.f;

    for (int jt = 0; jt < JC; jt += 64) {
        __syncthreads();  // all waves done reading previous tile
#pragma unroll
        for (int q = 0; q < 4; ++q) dma16(gA[q] + jt, lA[q]);
#pragma unroll
        for (int q = 0; q < 2; ++q) dma16(gH[q] + jt, lH[q]);
        __syncthreads();  // vmcnt(0) drain -> tiles visible

#pragma unroll
        for (int kh = 0; kh < 2; ++kh) {
            const int u0 = kh * 8 + quad * 2;                   // even
            const int sw = li & 7;
            float4 a0 = *(const float4*)&A_st[((iw + li) * 16 + (u0 ^ sw)) * 4];
            float4 a1 = *(const float4*)&A_st[((iw + li) * 16 + ((u0 + 1) ^ sw)) * 4];
            const int jl = kh * 32 + quad * 8;
            float4 s0 = *(const float4*)&s_ch[jt + jl];
            float4 s1 = *(const float4*)&s_ch[jt + jl + 4];
            float av[8] = {a0.x, a0.y, a0.z, a0.w, a1.x, a1.y, a1.z, a1.w};
            float sv[8] = {s0.x, s0.y, s0.z, s0.w, s1.x, s1.y, s1.z, s1.w};
            union { bf16x8 v; unsigned u[4]; } P;
#pragma unroll
            for (int p = 0; p < 4; ++p) {
                float x0 = s_i + sv[2 * p + 0];
                float x1 = s_i + sv[2 * p + 1];
                float w0 = __expf(fmaxf(x0, NEG * x0) + (av[2 * p + 0] - mb));
                float w1 = __expf(fmaxf(x1, NEG * x1) + (av[2 * p + 1] - mb));
                zsum += w0 + w1;
                P.u[p] = ((unsigned)f2bf(w1) << 16) | (unsigned)f2bf(w0);
            }
#pragma unroll
            for (int db = 0; db < 4; ++db) {
                int slotH = (db * 16 + li) * 8 + ((kh * 4 + quad) ^ sw);
                bf16x8 hf = *(const bf16x8*)&hT_st[slotH * 8];
                acc[db] = __builtin_amdgcn_mfma_f32_16x16x32_bf16(P.v, hf, acc[db], 0, 0, 0);
            }
        }
    }

    zsum += __shfl_xor(zsum, 16);
    zsum += __shfl_xor(zsum, 32);
    if (quad == 0) atomicAdd(&Z[head * N + myrow], zsum);

#pragma unroll
    for (int r = 0; r < 4; ++r) {
        float* op = &out[(size_t)(i0 + iw + quad * 4 + r) * OUT_F + head * D];
#pragma unroll
        for (int db = 0; db < 4; ++db) atomicAdd(&op[db * 16 + li], acc[db][r]);
    }
}

// ---- K4: normalize
__global__ __launch_bounds__(256) void k_norm(float* __restrict__ out,
                                              const float* __restrict__ Z) {
    int idx = blockIdx.x * 256 + threadIdx.x;
    int i = idx >> 9, hd = idx & 511, hh = hd >> 6;
    out[idx] = out[idx] / Z[hh * N + i];
}

extern "C" void kernel_launch(void* const* d_in, const int* in_sizes, int n_in,
                              void* d_out, int out_size, void* d_ws, size_t ws_size,
                              hipStream_t stream) {
    const float* inp = (const float*)d_in[0];
    const float* A = (const float*)d_in[1];
    const float* W = (const float*)d_in[2];
    const float* a_left = (const float*)d_in[3];
    float* out = (float*)d_out;

    // ws layout: hbT (4MB) | s (128KB) | Z (128KB) | smaxU (32B) | rmax (16KB)
    unsigned short* hbT = (unsigned short*)d_ws;
    float* s = (float*)((char*)d_ws + (size_t)H * D * N * 2);
    float* Z = s + (size_t)H * N;
    unsigned* smaxU = (unsigned*)(Z + (size_t)H * N);
    float* rmax = (float*)(smaxU + 8);

    hipMemsetAsync(out, 0, (size_t)N * OUT_F * sizeof(float), stream);
    hipMemsetAsync(Z, 0, (size_t)H * N * sizeof(float) + 8 * sizeof(unsigned), stream);

    k_gemm<<<dim3(N / 64, H), 256, 0, stream>>>(inp, W, a_left, hbT, s, smaxU);
    k_rowmax<<<dim3(N), 256, 0, stream>>>(A, rmax);
    k_attn<<<dim3(N / 64, H, N / JC), 256, 0, stream>>>(A, hbT, s, smaxU, rmax, out, Z);
    k_norm<<<dim3(N * OUT_F / 256), 256, 0, stream>>>(out, Z);
}

// Round 4
// 197.341 us; speedup vs baseline: 4.3560x; 1.4488x over previous
//
#include <hip/hip_runtime.h>
#include <math.h>

#define N 4096
#define IN_F 256
#define OUT_F 512
#define H 8
#define D 64
#define NEG 0.2f
#define JC 2048  // j-chunk per block (grid.z = 2)

typedef __attribute__((ext_vector_type(8))) short bf16x8;
typedef __attribute__((ext_vector_type(4))) float f32x4;

__device__ __forceinline__ float leaky(float x) { return fmaxf(x, NEG * x); }

__device__ __forceinline__ unsigned short f2bf(float x) {
    union { float f; unsigned u; } v; v.f = x;
    unsigned r = v.u + 0x7fff + ((v.u >> 16) & 1);  // RNE
    return (unsigned short)(r >> 16);
}

// monotone float<->uint map for atomicMax-based float max
__device__ __forceinline__ unsigned fmap(float x) {
    union { float f; unsigned u; } v; v.f = x;
    return (v.u & 0x80000000u) ? ~v.u : (v.u | 0x80000000u);
}
__device__ __forceinline__ float funmap(unsigned m) {
    union { float f; unsigned u; } v;
    v.u = (m & 0x80000000u) ? (m & 0x7fffffffu) : ~m;
    return v.f;
}

// async 16B global->LDS DMA
__device__ __forceinline__ void dma16(const void* g, void* l) {
    __builtin_amdgcn_global_load_lds((const __attribute__((address_space(1))) void*)g,
                                     (__attribute__((address_space(3))) void*)l, 16, 0, 0);
}

// ---- K1: h = inp @ W^T per (i-tile, head). BK=64, register-prefetch double buffer.
// Epilogue: scores s + block-reduced smax + bf16 transpose to hbT[h][d][j].
__global__ __launch_bounds__(256) void k_gemm(const float* __restrict__ inp,
                                              const float* __restrict__ W,
                                              const float* __restrict__ a_left,
                                              unsigned short* __restrict__ hbT,
                                              float* __restrict__ s,
                                              unsigned* __restrict__ smaxU) {
    __shared__ float As[64][68];  // [k][i] 17.4 KB
    __shared__ float Bs[64][68];  // [k][o] 17.4 KB
    __shared__ unsigned short h_st[64][72];
    __shared__ float s_red[64];

    const int t = threadIdx.x;
    const int bi = blockIdx.x;
    const int head = blockIdx.y;
    const int ty = t >> 4, tx = t & 15;
    const int lr = t >> 2;            // 0..63 row within tile
    const int cq = (t & 3) * 16;      // k sub-offset

    float4 pa[4], pb[4];
    auto loadrk = [&](int k0) {
        const float* ip = &inp[(size_t)(bi * 64 + lr) * IN_F + k0 + cq];
        const float* wp = &W[(size_t)(head * 64 + lr) * IN_F + k0 + cq];
#pragma unroll
        for (int q = 0; q < 4; ++q) {
            pa[q] = *(const float4*)&ip[q * 4];
            pb[q] = *(const float4*)&wp[q * 4];
        }
    };
    loadrk(0);

    float acc[4][4] = {};
    for (int k0 = 0; k0 < IN_F; k0 += 64) {
        __syncthreads();
#pragma unroll
        for (int q = 0; q < 4; ++q)
#pragma unroll
            for (int j = 0; j < 4; ++j) {
                As[cq + q * 4 + j][lr] = ((const float*)&pa[q])[j];
                Bs[cq + q * 4 + j][lr] = ((const float*)&pb[q])[j];
            }
        __syncthreads();
        if (k0 + 64 < IN_F) loadrk(k0 + 64);  // prefetch next slice, hidden by compute
#pragma unroll
        for (int k = 0; k < 64; ++k) {
            float4 a4 = *(const float4*)&As[k][ty * 4];
            float4 b4 = *(const float4*)&Bs[k][tx * 4];
            float a[4] = {a4.x, a4.y, a4.z, a4.w};
            float b[4] = {b4.x, b4.y, b4.z, b4.w};
#pragma unroll
            for (int r = 0; r < 4; ++r)
#pragma unroll
                for (int c = 0; c < 4; ++c) acc[r][c] = fmaf(a[r], b[c], acc[r][c]);
        }
    }

    // scores: s[head][i] = sum_d h[i][d]*a_left[head][d]
    float aL[4];
#pragma unroll
    for (int c = 0; c < 4; ++c) aL[c] = a_left[head * D + tx * 4 + c];
#pragma unroll
    for (int r = 0; r < 4; ++r) {
        float sp = acc[r][0] * aL[0] + acc[r][1] * aL[1] + acc[r][2] * aL[2] + acc[r][3] * aL[3];
        sp += __shfl_xor(sp, 1); sp += __shfl_xor(sp, 2);
        sp += __shfl_xor(sp, 4); sp += __shfl_xor(sp, 8);
        if (tx == 0) {
            s[head * N + bi * 64 + ty * 4 + r] = sp;
            s_red[ty * 4 + r] = sp;
        }
    }
    __syncthreads();
    if (t < 64) {  // block-level max -> ONE atomic per block
        float m = s_red[t];
        for (int off = 32; off; off >>= 1) m = fmaxf(m, __shfl_down(m, off, 64));
        if (t == 0) atomicMax(&smaxU[head], fmap(m));
    }

    // stage h tile as bf16 and transpose to hbT[head][d][i]
#pragma unroll
    for (int r = 0; r < 4; ++r) {
        ushort4 v;
        v.x = f2bf(acc[r][0]); v.y = f2bf(acc[r][1]);
        v.z = f2bf(acc[r][2]); v.w = f2bf(acc[r][3]);
        *(ushort4*)&h_st[ty * 4 + r][tx * 4] = v;
    }
    __syncthreads();
    {
        const int d = t >> 2, iq = (t & 3) * 16;
        unsigned short us[16];
#pragma unroll
        for (int k = 0; k < 16; ++k) us[k] = h_st[iq + k][d];
        unsigned short* dst = &hbT[((size_t)(head * D + d)) * N + bi * 64 + iq];
#pragma unroll
        for (int q = 0; q < 4; ++q) {
            ushort4 v = {us[q * 4 + 0], us[q * 4 + 1], us[q * 4 + 2], us[q * 4 + 3]};
            *(ushort4*)&dst[q * 4] = v;
        }
    }
}

// ---- K2: per-row max of A
__global__ __launch_bounds__(256) void k_rowmax(const float* __restrict__ A,
                                                float* __restrict__ rmax) {
    int i = blockIdx.x;
    const float* row = &A[(size_t)i * N];
    float m = -1e30f;
    for (int j = threadIdx.x * 4; j < N; j += 256 * 4) {
        float4 v = *(const float4*)&row[j];
        m = fmaxf(fmaxf(fmaxf(m, v.x), fmaxf(v.y, v.z)), v.w);
    }
    for (int off = 32; off; off >>= 1) m = fmaxf(m, __shfl_down(m, off, 64));
    __shared__ float red[4];
    if ((threadIdx.x & 63) == 0) red[threadIdx.x >> 6] = m;
    __syncthreads();
    if (threadIdx.x == 0) rmax[i] = fmaxf(fmaxf(red[0], red[1]), fmaxf(red[2], red[3]));
}

// ---- K3: fused attention. Block = (64 i-rows, head, j-half). DMA staging + XOR-swizzled LDS.
__global__ __launch_bounds__(256, 4) void k_attn(const float* __restrict__ A,
                                                 const unsigned short* __restrict__ hbT,
                                                 const float* __restrict__ s,
                                                 const unsigned* __restrict__ smaxU,
                                                 const float* __restrict__ rmax,
                                                 float* __restrict__ out,
                                                 float* __restrict__ Z) {
    __shared__ float A_st[64 * 16 * 4];          // 1024 slots x 16B, swizzled
    __shared__ unsigned short hT_st[64 * 8 * 8]; // 512 slots x 16B, swizzled
    __shared__ float s_ch[JC];

    const int t = threadIdx.x;
    const int i0 = blockIdx.x * 64;
    const int head = blockIdx.y;
    const int j0 = blockIdx.z * JC;
    const int lane = t & 63, wave = t >> 6, quad = lane >> 4, li = lane & 15;
    const int iw = wave * 16;
    const int myrow = i0 + iw + li;

#pragma unroll
    for (int q = 0; q < 2; ++q) {
        int idx = q * 256 + t;
        *(float4*)&s_ch[idx * 4] = *(const float4*)&s[head * N + j0 + idx * 4];
    }
    const float s_i = s[head * N + myrow];
    const float mb = leaky(s_i + funmap(smaxU[head])) + rmax[myrow];

    const float* gA[4]; void* lA[4];
#pragma unroll
    for (int q = 0; q < 4; ++q) {
        int slot = q * 256 + t;
        int r = slot >> 4, c4p = slot & 15;
        int c4 = c4p ^ (r & 7);
        gA[q] = &A[(size_t)(i0 + r) * N + j0 + c4 * 4];
        lA[q] = (void*)&A_st[slot * 4];
    }
    const unsigned short* gH[2]; void* lH[2];
#pragma unroll
    for (int q = 0; q < 2; ++q) {
        int slot = q * 256 + t;
        int r = slot >> 3, u = slot & 7;
        int uc = u ^ (r & 7);
        gH[q] = &hbT[(size_t)head * D * N + (size_t)r * N + j0 + uc * 8];
        lH[q] = (void*)&hT_st[slot * 8];
    }

    f32x4 acc[4] = {{0, 0, 0, 0}, {0, 0, 0, 0}, {0, 0, 0, 0}, {0, 0, 0, 0}};
    float zsum = 0.f;

    for (int jt = 0; jt < JC; jt += 64) {
        __syncthreads();
#pragma unroll
        for (int q = 0; q < 4; ++q) dma16(gA[q] + jt, lA[q]);
#pragma unroll
        for (int q = 0; q < 2; ++q) dma16(gH[q] + jt, lH[q]);
        __syncthreads();

#pragma unroll
        for (int kh = 0; kh < 2; ++kh) {
            const int u0 = kh * 8 + quad * 2;
            const int sw = li & 7;
            float4 a0 = *(const float4*)&A_st[((iw + li) * 16 + (u0 ^ sw)) * 4];
            float4 a1 = *(const float4*)&A_st[((iw + li) * 16 + ((u0 + 1) ^ sw)) * 4];
            const int jl = kh * 32 + quad * 8;
            float4 s0 = *(const float4*)&s_ch[jt + jl];
            float4 s1 = *(const float4*)&s_ch[jt + jl + 4];
            float av[8] = {a0.x, a0.y, a0.z, a0.w, a1.x, a1.y, a1.z, a1.w};
            float sv[8] = {s0.x, s0.y, s0.z, s0.w, s1.x, s1.y, s1.z, s1.w};
            union { bf16x8 v; unsigned u[4]; } P;
#pragma unroll
            for (int p = 0; p < 4; ++p) {
                float x0 = s_i + sv[2 * p + 0];
                float x1 = s_i + sv[2 * p + 1];
                float w0 = __expf(fmaxf(x0, NEG * x0) + (av[2 * p + 0] - mb));
                float w1 = __expf(fmaxf(x1, NEG * x1) + (av[2 * p + 1] - mb));
                zsum += w0 + w1;
                P.u[p] = ((unsigned)f2bf(w1) << 16) | (unsigned)f2bf(w0);
            }
#pragma unroll
            for (int db = 0; db < 4; ++db) {
                int slotH = (db * 16 + li) * 8 + ((kh * 4 + quad) ^ sw);
                bf16x8 hf = *(const bf16x8*)&hT_st[slotH * 8];
                acc[db] = __builtin_amdgcn_mfma_f32_16x16x32_bf16(P.v, hf, acc[db], 0, 0, 0);
            }
        }
    }

    zsum += __shfl_xor(zsum, 16);
    zsum += __shfl_xor(zsum, 32);
    if (quad == 0) atomicAdd(&Z[head * N + myrow], zsum);

#pragma unroll
    for (int r = 0; r < 4; ++r) {
        float* op = &out[(size_t)(i0 + iw + quad * 4 + r) * OUT_F + head * D];
#pragma unroll
        for (int db = 0; db < 4; ++db) atomicAdd(&op[db * 16 + li], acc[db][r]);
    }
}

// ---- K4: normalize
__global__ __launch_bounds__(256) void k_norm(float* __restrict__ out,
                                              const float* __restrict__ Z) {
    int idx = blockIdx.x * 256 + threadIdx.x;
    int i = idx >> 9, hd = idx & 511, hh = hd >> 6;
    out[idx] = out[idx] / Z[hh * N + i];
}

extern "C" void kernel_launch(void* const* d_in, const int* in_sizes, int n_in,
                              void* d_out, int out_size, void* d_ws, size_t ws_size,
                              hipStream_t stream) {
    const float* inp = (const float*)d_in[0];
    const float* A = (const float*)d_in[1];
    const float* W = (const float*)d_in[2];
    const float* a_left = (const float*)d_in[3];
    float* out = (float*)d_out;

    // ws layout: hbT (4MB) | s (128KB) | Z (128KB) | smaxU (32B) | rmax (16KB)
    unsigned short* hbT = (unsigned short*)d_ws;
    float* s = (float*)((char*)d_ws + (size_t)H * D * N * 2);
    float* Z = s + (size_t)H * N;
    unsigned* smaxU = (unsigned*)(Z + (size_t)H * N);
    float* rmax = (float*)(smaxU + 8);

    hipMemsetAsync(out, 0, (size_t)N * OUT_F * sizeof(float), stream);
    hipMemsetAsync(Z, 0, (size_t)H * N * sizeof(float) + 8 * sizeof(unsigned), stream);

    k_gemm<<<dim3(N / 64, H), 256, 0, stream>>>(inp, W, a_left, hbT, s, smaxU);
    k_rowmax<<<dim3(N), 256, 0, stream>>>(A, rmax);
    k_attn<<<dim3(N / 64, H, N / JC), 256, 0, stream>>>(A, hbT, s, smaxU, rmax, out, Z);
    k_norm<<<dim3(N * OUT_F / 256), 256, 0, stream>>>(out, Z);
}